// Round 1
// baseline (632.269 us; speedup 1.0000x reference)
//
#include <hip/hip_runtime.h>
#include <math.h>

#define NN 100000
#define NPAD 100096
#define NT3 3128      // NPAD / 32 (gru blocks)
#define NE 800000
#define DD 128
#define SCANB 98      // ceil(NN/1024)

typedef __attribute__((ext_vector_type(8))) short short8;
typedef __attribute__((ext_vector_type(4))) float floatx4;
typedef unsigned short ush_t;
typedef __attribute__((ext_vector_type(8))) unsigned short ushort8_t;

__device__ __forceinline__ ush_t f2bf(float f) {
    unsigned u = __float_as_uint(f);
    return (ush_t)((u + 0x7fffu + ((u >> 16) & 1u)) >> 16);
}
__device__ __forceinline__ float bf2f(ush_t h) {
    return __uint_as_float((unsigned)h << 16);
}
__device__ __forceinline__ float sigf(float x) {
    return __builtin_amdgcn_rcpf(1.0f + __expf(-x));
}
__device__ __forceinline__ float tanhf_fast(float x) {
    x = fminf(fmaxf(x, -20.0f), 20.0f);
    float e = __expf(2.0f * x);
    return 1.0f - 2.0f * __builtin_amdgcn_rcpf(e + 1.0f);
}

// ---------------------------------------------------------------- row means of edge-type table
__global__ void rowmean_kernel(const float* __restrict__ tab, float* __restrict__ rm) {
    int r = blockIdx.x;
    int t = threadIdx.x;
    float v = tab[r * DD + t];
    #pragma unroll
    for (int o = 32; o > 0; o >>= 1) v += __shfl_xor(v, o);
    __shared__ float red[2];
    if ((t & 63) == 0) red[t >> 6] = v;
    __syncthreads();
    if (t == 0) rm[r] = (red[0] + red[1]) * (1.0f / DD);
}

// ---------------------------------------------------------------- CSR build
__global__ void hist_kernel(const int* __restrict__ dst, int* __restrict__ fill) {
    int e = blockIdx.x * 256 + threadIdx.x;
    if (e < NE) atomicAdd(&fill[dst[e]], 1);
}

__global__ __launch_bounds__(1024) void scanA_kernel(const int* __restrict__ cnt,
                                                     int* __restrict__ rp,
                                                     int* __restrict__ bsum) {
    __shared__ int wsum[16];
    int t = threadIdx.x;
    int i = blockIdx.x * 1024 + t;
    int lane = t & 63, w = t >> 6;
    int v = (i < NN) ? cnt[i] : 0;
    int sv = v;
    #pragma unroll
    for (int off = 1; off < 64; off <<= 1) {
        int u = __shfl_up(sv, off);
        if (lane >= off) sv += u;
    }
    if (lane == 63) wsum[w] = sv;
    __syncthreads();
    int woff = 0;
    #pragma unroll
    for (int j = 0; j < 16; ++j) woff += (j < w) ? wsum[j] : 0;
    if (i < NN) rp[i + 1] = sv + woff;
    if (t == 1023) bsum[blockIdx.x] = sv + woff;
}

__global__ __launch_bounds__(128) void scanB_kernel(const int* __restrict__ bsum,
                                                    int* __restrict__ boff) {
    __shared__ int wsum[2];
    int t = threadIdx.x;
    int lane = t & 63, w = t >> 6;
    int v = (t < SCANB) ? bsum[t] : 0;
    int sv = v;
    #pragma unroll
    for (int off = 1; off < 64; off <<= 1) {
        int u = __shfl_up(sv, off);
        if (lane >= off) sv += u;
    }
    if (lane == 63) wsum[w] = sv;
    __syncthreads();
    int woff = (w == 1) ? wsum[0] : 0;
    if (t < SCANB) boff[t] = sv + woff - v;   // exclusive
}

__global__ __launch_bounds__(256) void scanC_kernel(int* __restrict__ rp,
                                                    const int* __restrict__ boff) {
    int i = blockIdx.x * 256 + threadIdx.x;
    if (i == 0) rp[0] = 0;
    if (i < NN) rp[i + 1] += boff[i >> 10];
}

// single interleaved 8B record per edge: (src, weight-bits) — one scattered
// store instead of two (R13: two 4B streams cost 85MB of line-granular writes)
__global__ void place_kernel(const int* __restrict__ src, const int* __restrict__ dst,
                             const int* __restrict__ et, const float* __restrict__ rm,
                             const int* __restrict__ rp, int* __restrict__ fill,
                             uint2* __restrict__ csr) {
    int e = blockIdx.x * 256 + threadIdx.x;
    if (e < NE) {
        int d = dst[e];
        int pos = rp[d] + atomicAdd(&fill[d], 1);
        uint2 rec;
        rec.x = (unsigned)src[e];
        rec.y = __float_as_uint(rm[et[e] - 1]);
        csr[pos] = rec;
    }
}

// ---------------------------------------------------------------- embedding gather → bf16 row-major
__global__ void embed_kernel(const int* __restrict__ ids, const float* __restrict__ tab,
                             ush_t* __restrict__ x) {
    int tid = blockIdx.x * 256 + threadIdx.x;   // NPAD*16
    int n = tid >> 4, c = tid & 15;
    if (n >= NPAD) return;
    ushort8_t h;
    if (n < NN) {
        const float4* srcp = (const float4*)(tab + (size_t)(ids[n] + 1) * DD + c * 8);
        float4 v0 = srcp[0], v1 = srcp[1];
        h[0] = f2bf(v0.x); h[1] = f2bf(v0.y); h[2] = f2bf(v0.z); h[3] = f2bf(v0.w);
        h[4] = f2bf(v1.x); h[5] = f2bf(v1.y); h[6] = f2bf(v1.z); h[7] = f2bf(v1.w);
    } else {
        #pragma unroll
        for (int e = 0; e < 8; ++e) h[e] = 0;
    }
    *(ushort8_t*)(x + (size_t)n * DD + c * 8) = h;
}

// ---------------------------------------------------------------- weight prep: Whh gates → WB mats 0..2
__global__ void wprep_kernel(const float* __restrict__ Whh, ush_t* __restrict__ WB) {
    int idx = blockIdx.x * 256 + threadIdx.x;   // 3*16384
    int mat = idx >> 14;
    int rem = idx & 16383;
    int col = rem & 127, kk = rem >> 7;
    float w = Whh[((size_t)mat * 128 + col) * 128 + kk];
    int chunk = kk >> 5, klo = kk & 31;
    int inoff = ((col >> 4) * 4 + (klo >> 3)) * 128 + (col & 15) * 8 + (klo & 7);
    WB[(size_t)(mat * 4 + chunk) * 4096 + inoff] = f2bf(w);
}

// ---------------------------------------------------------------- combined weights: C[l,g] = W_l @ Wih_g^T
__global__ __launch_bounds__(256) void cprep_kernel(const float* __restrict__ Wih,
                                                    const float* __restrict__ G,
                                                    ush_t* __restrict__ WB) {
    __shared__ float sW[16 * 128];
    int b = blockIdx.x;                 // 96 = 12 mats * 8 rowgroups
    int mat = b >> 3, rg = b & 7;
    int l = mat / 3, g = mat % 3;
    int k0 = rg * 16;
    int t = threadIdx.x;
    #pragma unroll
    for (int it = 0; it < 8; ++it) {
        int idx = it * 256 + t;
        sW[idx] = G[(size_t)l * 16384 + (size_t)(k0 + (idx >> 7)) * 128 + (idx & 127)];
    }
    __syncthreads();
    int col = t & 127, kh = t >> 7;
    float acc[8];
    #pragma unroll
    for (int e = 0; e < 8; ++e) acc[e] = 0.f;
    const float* wr = Wih + (size_t)(g * 128 + col) * 128;
    for (int j = 0; j < 128; ++j) {
        float wv = wr[j];
        #pragma unroll
        for (int e = 0; e < 8; ++e) acc[e] += sW[(kh * 8 + e) * 128 + j] * wv;
    }
    int M = 3 + l * 3 + g;
    #pragma unroll
    for (int e = 0; e < 8; ++e) {
        int k = k0 + kh * 8 + e;
        int chunk = k >> 5, klo = k & 31;
        int inoff = ((col >> 4) * 4 + (klo >> 3)) * 128 + (col & 15) * 8 + (klo & 7);
        WB[(size_t)(M * 4 + chunk) * 4096 + inoff] = f2bf(acc[e]);
    }
}

// ---------------------------------------------------------------- fused gather + GRU layer kernel
// Gather for node block [n0,n0+32) depends only on xin (previous layer), so it
// fuses into the gru block with no cross-block dependency. Gathered rows land
// row-major in LDS (sG, pitch 136 like sX) so pass-1 A-frag reads are the same
// ds_read_b128 pattern as pass-0. Removes the 51MB/layer gH round-trip and the
// agg<->gru serialization; gather-latency of one block overlaps MFMA of others.
__global__ __launch_bounds__(256, 4) void gru_kernel(const ush_t* __restrict__ xin,
                                                     const int* __restrict__ rp,
                                                     const uint2* __restrict__ csr,
                                                     ush_t* __restrict__ xout,
                                                     const ush_t* __restrict__ WB,
                                                     const float* __restrict__ bih,
                                                     const float* __restrict__ bhh,
                                                     int layer, int is_last,
                                                     const float* __restrict__ gw,
                                                     const float* __restrict__ gb,
                                                     float* __restrict__ accum,
                                                     float* __restrict__ den) {
    __shared__ ush_t sX[32 * 136];
    __shared__ ush_t sG[32 * 136];
    __shared__ float pl[32];
    __shared__ float sT[128];
    int t = threadIdx.x;
    int tb = blockIdx.x;
    int n0 = tb * 32;
    // --- stage x tile (row-major, padded pitch) — independent coalesced loads first
    #pragma unroll
    for (int it = 0; it < 2; ++it) {
        int idx = it * 256 + t;          // 512 chunks of 16B
        int row = idx >> 4, seg = idx & 15;
        ushort8_t v = *(const ushort8_t*)(xin + (size_t)(n0 + row) * DD + seg * 8);
        *(ushort8_t*)(sX + row * 136 + seg * 8) = v;
    }
    // --- fused CSR gather: 8 groups of 32 lanes, 4 rows per group
    {
        int grp = t >> 5, c = t & 31;
        #pragma unroll
        for (int it = 0; it < 4; ++it) {
            int row = grp * 4 + it;
            int n = n0 + row;
            float4 acc = make_float4(0.f, 0.f, 0.f, 0.f);
            if (n < NN) {
                int e0 = rp[n], e1 = rp[n + 1];
                int e = e0;
                for (; e + 1 < e1; e += 2) {
                    uint2 r0 = csr[e], r1 = csr[e + 1];
                    float w0 = __uint_as_float(r0.y), w1 = __uint_as_float(r1.y);
                    ushort4 p0 = *(const ushort4*)(xin + (size_t)r0.x * DD + c * 4);
                    ushort4 p1 = *(const ushort4*)(xin + (size_t)r1.x * DD + c * 4);
                    acc.x += w0 * bf2f(p0.x) + w1 * bf2f(p1.x);
                    acc.y += w0 * bf2f(p0.y) + w1 * bf2f(p1.y);
                    acc.z += w0 * bf2f(p0.z) + w1 * bf2f(p1.z);
                    acc.w += w0 * bf2f(p0.w) + w1 * bf2f(p1.w);
                }
                if (e < e1) {
                    uint2 r0 = csr[e];
                    float w0 = __uint_as_float(r0.y);
                    ushort4 p0 = *(const ushort4*)(xin + (size_t)r0.x * DD + c * 4);
                    acc.x += w0 * bf2f(p0.x);
                    acc.y += w0 * bf2f(p0.y);
                    acc.z += w0 * bf2f(p0.z);
                    acc.w += w0 * bf2f(p0.w);
                }
            }
            ushort4 oh;
            oh.x = f2bf(acc.x); oh.y = f2bf(acc.y); oh.z = f2bf(acc.z); oh.w = f2bf(acc.w);
            *(ushort4*)(sG + row * 136 + c * 4) = oh;   // 2-way bank alias only (free)
        }
    }
    __syncthreads();
    // --- MFMA: pass0 = sX vs Whh-gates, pass1 = sG vs combined weights
    int l = t & 63, w = t >> 6;
    int lg = l >> 4, lc = l & 15;
    floatx4 accR[2][2], accZ[2][2], accN[2][2], accI[2][2];
    #pragma unroll
    for (int i = 0; i < 2; ++i)
        #pragma unroll
        for (int j = 0; j < 2; ++j) {
            accR[i][j] = (floatx4)0.f; accZ[i][j] = (floatx4)0.f;
            accN[i][j] = (floatx4)0.f; accI[i][j] = (floatx4)0.f;
        }
    #pragma unroll
    for (int pass = 0; pass < 2; ++pass) {
        int matbase = pass ? (3 + layer * 3) : 0;
        const ush_t* sp = pass ? sG : sX;
        #pragma unroll
        for (int kc = 0; kc < 4; ++kc) {
            short8 aHf[2];
            #pragma unroll
            for (int i = 0; i < 2; ++i)
                aHf[i] = *(const short8*)(sp + (i * 16 + lc) * 136 + kc * 32 + lg * 8);
            #pragma unroll
            for (int m3 = 0; m3 < 3; ++m3) {
                floatx4 (*accp)[2] = (m3 == 0) ? accR : (m3 == 1) ? accZ : (pass ? accI : accN);
                const ush_t* wb = WB + (size_t)((matbase + m3) * 4 + kc) * 4096;
                #pragma unroll
                for (int j = 0; j < 2; ++j) {
                    int boff = (((w * 2 + j) * 4 + lg) * 16 + lc) * 8;
                    short8 bH = *(const short8*)(wb + boff);
                    #pragma unroll
                    for (int i = 0; i < 2; ++i)
                        accp[i][j] = __builtin_amdgcn_mfma_f32_16x16x32_bf16(aHf[i], bH, accp[i][j], 0, 0, 0);
                }
            }
        }
    }
    __syncthreads();   // all sX A-frag reads done before overwrite
    // --- gates + blend, in-place into sX
    #pragma unroll
    for (int j = 0; j < 2; ++j) {
        int col = w * 32 + j * 16 + lc;
        float bIr = bih[col],       bHr = bhh[col];
        float bIz = bih[128 + col], bHz = bhh[128 + col];
        float bIn = bih[256 + col], bHn = bhh[256 + col];
        #pragma unroll
        for (int i = 0; i < 2; ++i)
            #pragma unroll
            for (int r = 0; r < 4; ++r) {
                int row = i * 16 + lg * 4 + r;
                float v = 0.f;
                if (n0 + row < NN) {
                    float rr = sigf(accR[i][j][r] + bIr + bHr);
                    float zz = sigf(accZ[i][j][r] + bIz + bHz);
                    float nn = tanhf_fast(accI[i][j][r] + bIn + rr * (accN[i][j][r] + bHn));
                    float h = bf2f(sX[row * 136 + col]);
                    v = (1.0f - zz) * nn + zz * h;
                }
                sX[row * 136 + col] = f2bf(v);
            }
    }
    __syncthreads();
    if (!is_last) {
        // --- coalesced row-major write-out
        #pragma unroll
        for (int it = 0; it < 2; ++it) {
            int idx = it * 256 + t;
            int row = idx >> 4, seg = idx & 15;
            ushort8_t v = *(const ushort8_t*)(sX + row * 136 + seg * 8);
            *(ushort8_t*)(xout + (size_t)(n0 + row) * DD + seg * 8) = v;
        }
    } else {
        // --- fused global-attention pooling (replicated accumulators)
        int row = t >> 3, q = t & 7;      // 8 threads per row, 16 cols each
        float s = 0.f;
        #pragma unroll
        for (int e = 0; e < 16; ++e)
            s += bf2f(sX[row * 136 + q * 16 + e]) * gw[q * 16 + e];
        s += __shfl_xor(s, 1);
        s += __shfl_xor(s, 2);
        s += __shfl_xor(s, 4);
        if (q == 0)
            pl[row] = (n0 + row < NN) ? __expf(sigf(s + gb[0])) : 0.f;
        __syncthreads();
        int cc = t & 127, half = t >> 7;
        float acc = 0.f;
        #pragma unroll
        for (int r = 0; r < 16; ++r)
            acc += pl[half * 16 + r] * bf2f(sX[(half * 16 + r) * 136 + cc]);
        if (half == 0) sT[cc] = acc;
        __syncthreads();
        if (half == 1) atomicAdd(&accum[(tb & 63) * 128 + cc], acc + sT[cc]);
        if (t < 32) {
            float v = pl[t];
            #pragma unroll
            for (int o = 16; o > 0; o >>= 1) v += __shfl_xor(v, o);
            if (t == 0) atomicAdd(&den[tb & 63], v);
        }
    }
}

__global__ void finalize_kernel(const float* __restrict__ accum, const float* __restrict__ den,
                                float* __restrict__ out) {
    __shared__ float dsum;
    int d = threadIdx.x;   // 128
    float s = 0.f;
    for (int rep = 0; rep < 64; ++rep) s += accum[rep * 128 + d];
    if (d == 0) {
        float ds = 0.f;
        for (int rep = 0; rep < 64; ++rep) ds += den[rep];
        dsum = ds;
    }
    __syncthreads();
    out[d] = s / dsum;
}

// ---------------------------------------------------------------- launch
extern "C" void kernel_launch(void* const* d_in, const int* in_sizes, int n_in,
                              void* d_out, int out_size, void* d_ws, size_t ws_size,
                              hipStream_t stream) {
    const int*   node_ids    = (const int*)d_in[0];
    const int*   edges       = (const int*)d_in[1];
    const int*   edge_types  = (const int*)d_in[2];
    const float* embed_table = (const float*)d_in[3];
    const float* edge_tab    = (const float*)d_in[4];
    const float* ggnn_w      = (const float*)d_in[5];
    const float* Wih         = (const float*)d_in[6];
    const float* Whh         = (const float*)d_in[7];
    const float* bih         = (const float*)d_in[8];
    const float* bhh         = (const float*)d_in[9];
    const float* gate_w      = (const float*)d_in[10];
    const float* gate_b      = (const float*)d_in[11];
    float* out = (float*)d_out;

    const size_t PL = (size_t)NPAD * DD;
    ush_t* wsb  = (ush_t*)d_ws;
    ush_t* xA   = wsb;
    ush_t* xB   = xA + PL;
    ush_t* gH   = xB + PL;          // (unused after fusion; kept for layout stability)
    ush_t* WB   = gH + PL;          // 15 mats * 4 chunks * 4096
    uint2* csr  = (uint2*)(WB + 15 * 4 * 4096);   // E records (8B-aligned)
    float* accum = (float*)(csr + NE);  // 64 * 128
    float* den   = accum + 64 * 128;    // 64
    float* rm    = den + 64;            // 7(+1)
    int*   rp    = (int*)(rm + 8);      // N+1
    int*   fill  = rp + NN + 1;         // N
    int*   bsum  = fill + NN;           // 128
    int*   boff  = bsum + 128;          // 128

    const int* src = edges;
    const int* dst = edges + NE;

    // one-time prep
    rowmean_kernel<<<7, 128, 0, stream>>>(edge_tab, rm);
    hipMemsetAsync(fill, 0, NN * sizeof(int), stream);
    hist_kernel<<<(NE + 255) / 256, 256, 0, stream>>>(dst, fill);
    scanA_kernel<<<SCANB, 1024, 0, stream>>>(fill, rp, bsum);
    scanB_kernel<<<1, 128, 0, stream>>>(bsum, boff);
    scanC_kernel<<<(NN + 255) / 256, 256, 0, stream>>>(rp, boff);
    hipMemsetAsync(fill, 0, NN * sizeof(int), stream);
    place_kernel<<<(NE + 255) / 256, 256, 0, stream>>>(src, dst, edge_types, rm, rp, fill, csr);
    embed_kernel<<<NPAD * 16 / 256, 256, 0, stream>>>(node_ids, embed_table, xA);
    wprep_kernel<<<192, 256, 0, stream>>>(Whh, WB);
    cprep_kernel<<<96, 256, 0, stream>>>(Wih, ggnn_w, WB);
    hipMemsetAsync(accum, 0, (64 * 128 + 64) * sizeof(float), stream);

    // 4 layers: fused gather + GRU
    ush_t* x = xA;
    ush_t* xo = xB;
    for (int layer = 0; layer < 4; ++layer) {
        gru_kernel<<<NT3, 256, 0, stream>>>(x, rp, csr, xo, WB, bih, bhh,
                                            layer, layer == 3 ? 1 : 0,
                                            gate_w, gate_b, accum, den);
        ush_t* tmp = x; x = xo; xo = tmp;
    }

    finalize_kernel<<<1, 128, 0, stream>>>(accum, den, out);
}

// Round 2
// 521.524 us; speedup vs baseline: 1.2123x; 1.2123x over previous
//
#include <hip/hip_runtime.h>
#include <math.h>

#define NN 100000
#define NPAD 100096
#define NT3 3128      // NPAD / 32 (gru blocks)
#define NE 800000
#define DD 128
#define SCANB 98      // ceil(NN/1024)

#define EMB_BLKS 6256     // NPAD*16/256
#define HIST_BLKS 3125    // NE/256
#define CPREP_BLKS 96
#define WPREP_BLKS 192
#define MEGA_BLKS (EMB_BLKS + HIST_BLKS + CPREP_BLKS + WPREP_BLKS + 7)

typedef __attribute__((ext_vector_type(8))) short short8;
typedef __attribute__((ext_vector_type(4))) float floatx4;
typedef unsigned short ush_t;
typedef __attribute__((ext_vector_type(8))) unsigned short ushort8_t;

__device__ __forceinline__ ush_t f2bf(float f) {
    unsigned u = __float_as_uint(f);
    return (ush_t)((u + 0x7fffu + ((u >> 16) & 1u)) >> 16);
}
__device__ __forceinline__ float bf2f(ush_t h) {
    return __uint_as_float((unsigned)h << 16);
}
__device__ __forceinline__ float sigf(float x) {
    return __builtin_amdgcn_rcpf(1.0f + __expf(-x));
}
__device__ __forceinline__ float tanhf_fast(float x) {
    x = fminf(fmaxf(x, -20.0f), 20.0f);
    float e = __expf(2.0f * x);
    return 1.0f - 2.0f * __builtin_amdgcn_rcpf(e + 1.0f);
}

// ---------------------------------------------------------------- mega-prep: embed + hist + cprep + wprep + rowmean
// All five are mutually independent one-time preps; merging them into one
// launch lets the gather-bound embed overlap the atomic-bound hist and the
// tiny matmul cprep instead of serializing 5 dispatches.
__global__ __launch_bounds__(256) void megaprep_kernel(
        const int* __restrict__ ids, const float* __restrict__ tab, ush_t* __restrict__ x,
        const int* __restrict__ dst, int* __restrict__ fill,
        const float* __restrict__ Wih, const float* __restrict__ G,
        const float* __restrict__ Whh, ush_t* __restrict__ WB,
        const float* __restrict__ etab, float* __restrict__ rm) {
    __shared__ float sW[16 * 128];
    int b = blockIdx.x;
    int t = threadIdx.x;
    if (b < EMB_BLKS) {
        // ---- embedding gather -> bf16 row-major
        int tid = b * 256 + t;
        int n = tid >> 4, c = tid & 15;
        ushort8_t h;
        if (n < NN) {
            const float4* srcp = (const float4*)(tab + (size_t)(ids[n] + 1) * DD + c * 8);
            float4 v0 = srcp[0], v1 = srcp[1];
            h[0] = f2bf(v0.x); h[1] = f2bf(v0.y); h[2] = f2bf(v0.z); h[3] = f2bf(v0.w);
            h[4] = f2bf(v1.x); h[5] = f2bf(v1.y); h[6] = f2bf(v1.z); h[7] = f2bf(v1.w);
        } else {
            #pragma unroll
            for (int e = 0; e < 8; ++e) h[e] = 0;
        }
        if (n < NPAD)
            *(ushort8_t*)(x + (size_t)n * DD + c * 8) = h;
        return;
    }
    b -= EMB_BLKS;
    if (b < HIST_BLKS) {
        // ---- degree histogram
        int e = b * 256 + t;
        if (e < NE) atomicAdd(&fill[dst[e]], 1);
        return;
    }
    b -= HIST_BLKS;
    if (b < CPREP_BLKS) {
        // ---- combined weights: C[l,g] = W_l @ Wih_g^T
        int mat = b >> 3, rg = b & 7;
        int l = mat / 3, g = mat % 3;
        int k0 = rg * 16;
        #pragma unroll
        for (int it = 0; it < 8; ++it) {
            int idx = it * 256 + t;
            sW[idx] = G[(size_t)l * 16384 + (size_t)(k0 + (idx >> 7)) * 128 + (idx & 127)];
        }
        __syncthreads();
        int col = t & 127, kh = t >> 7;
        float acc[8];
        #pragma unroll
        for (int e = 0; e < 8; ++e) acc[e] = 0.f;
        const float* wr = Wih + (size_t)(g * 128 + col) * 128;
        for (int j = 0; j < 128; ++j) {
            float wv = wr[j];
            #pragma unroll
            for (int e = 0; e < 8; ++e) acc[e] += sW[(kh * 8 + e) * 128 + j] * wv;
        }
        int M = 3 + l * 3 + g;
        #pragma unroll
        for (int e = 0; e < 8; ++e) {
            int k = k0 + kh * 8 + e;
            int chunk = k >> 5, klo = k & 31;
            int inoff = ((col >> 4) * 4 + (klo >> 3)) * 128 + (col & 15) * 8 + (klo & 7);
            WB[(size_t)(M * 4 + chunk) * 4096 + inoff] = f2bf(acc[e]);
        }
        return;
    }
    b -= CPREP_BLKS;
    if (b < WPREP_BLKS) {
        // ---- Whh gates -> WB mats 0..2
        int idx = b * 256 + t;
        int mat = idx >> 14;
        int rem = idx & 16383;
        int col = rem & 127, kk = rem >> 7;
        float w = Whh[((size_t)mat * 128 + col) * 128 + kk];
        int chunk = kk >> 5, klo = kk & 31;
        int inoff = ((col >> 4) * 4 + (klo >> 3)) * 128 + (col & 15) * 8 + (klo & 7);
        WB[(size_t)(mat * 4 + chunk) * 4096 + inoff] = f2bf(w);
        return;
    }
    b -= WPREP_BLKS;
    {
        // ---- row means of edge-type table (7 blocks)
        int r = b;
        float v = (t < 128) ? etab[r * DD + t] : 0.f;
        #pragma unroll
        for (int o = 32; o > 0; o >>= 1) v += __shfl_xor(v, o);
        if ((t & 63) == 0) sW[t >> 6] = v;
        __syncthreads();
        if (t == 0) rm[r] = (sW[0] + sW[1]) * (1.0f / DD);
    }
}

// ---------------------------------------------------------------- CSR build scans
__global__ __launch_bounds__(1024) void scanA_kernel(const int* __restrict__ cnt,
                                                     int* __restrict__ rp,
                                                     int* __restrict__ bsum) {
    __shared__ int wsum[16];
    int t = threadIdx.x;
    int i = blockIdx.x * 1024 + t;
    int lane = t & 63, w = t >> 6;
    int v = (i < NN) ? cnt[i] : 0;
    int sv = v;
    #pragma unroll
    for (int off = 1; off < 64; off <<= 1) {
        int u = __shfl_up(sv, off);
        if (lane >= off) sv += u;
    }
    if (lane == 63) wsum[w] = sv;
    __syncthreads();
    int woff = 0;
    #pragma unroll
    for (int j = 0; j < 16; ++j) woff += (j < w) ? wsum[j] : 0;
    if (i < NN) rp[i + 1] = sv + woff;
    if (t == 1023) bsum[blockIdx.x] = sv + woff;
}

__global__ __launch_bounds__(128) void scanB_kernel(const int* __restrict__ bsum,
                                                    int* __restrict__ boff,
                                                    float* __restrict__ accz) {
    __shared__ int wsum[2];
    int t = threadIdx.x;
    int lane = t & 63, w = t >> 6;
    int v = (t < SCANB) ? bsum[t] : 0;
    int sv = v;
    #pragma unroll
    for (int off = 1; off < 64; off <<= 1) {
        int u = __shfl_up(sv, off);
        if (lane >= off) sv += u;
    }
    if (lane == 63) wsum[w] = sv;
    __syncthreads();
    int woff = (w == 1) ? wsum[0] : 0;
    if (t < SCANB) boff[t] = sv + woff - v;   // exclusive
    // fold: zero the pooling accumulators (replaces a memset dispatch)
    for (int i = t; i < 64 * 128 + 64; i += 128) accz[i] = 0.f;
}

__global__ __launch_bounds__(256) void scanC_kernel(int* __restrict__ rp,
                                                    const int* __restrict__ boff,
                                                    int* __restrict__ fill) {
    int i = blockIdx.x * 256 + threadIdx.x;
    if (i == 0) rp[0] = 0;
    if (i < NN) {
        rp[i + 1] += boff[i >> 10];
        fill[i] = 0;   // fold: re-zero fill for place (replaces a memset dispatch)
    }
}

// single interleaved 8B record per edge: (src, weight-bits)
__global__ void place_kernel(const int* __restrict__ src, const int* __restrict__ dst,
                             const int* __restrict__ et, const float* __restrict__ rm,
                             const int* __restrict__ rp, int* __restrict__ fill,
                             uint2* __restrict__ csr) {
    int e = blockIdx.x * 256 + threadIdx.x;
    if (e < NE) {
        int d = dst[e];
        int pos = rp[d] + atomicAdd(&fill[d], 1);
        uint2 rec;
        rec.x = (unsigned)src[e];
        rec.y = __float_as_uint(rm[et[e] - 1]);
        csr[pos] = rec;
    }
}

// ---------------------------------------------------------------- CSR gather: g = sum ew*x[src]
// unroll-4: 4 contiguous csr records + 4 independent row loads in flight
__global__ __launch_bounds__(512) void agg_kernel(const ush_t* __restrict__ x,
                                                  const int* __restrict__ rp,
                                                  const uint2* __restrict__ csr,
                                                  ush_t* __restrict__ gH) {
    int t = threadIdx.x;
    int grp = t >> 5, c = t & 31;
    int n = blockIdx.x * 16 + grp;
    if (n >= NPAD) return;
    int nout = ((n >> 7) << 14) + ((c >> 3) << 12) + (((n >> 4) & 7) << 9)
             + (((c >> 1) & 3) << 7) + ((n & 15) << 3) + ((c & 1) << 2);
    if (n >= NN) {
        *(ushort4*)(gH + nout) = make_ushort4(0, 0, 0, 0);
        return;
    }
    const ush_t* xc = x + c * 4;
    int e0 = rp[n], e1 = rp[n + 1];
    float4 acc = make_float4(0.f, 0.f, 0.f, 0.f);
    int e = e0;
    for (; e + 3 < e1; e += 4) {
        uint2 r0 = csr[e], r1 = csr[e + 1], r2 = csr[e + 2], r3 = csr[e + 3];
        float w0 = __uint_as_float(r0.y), w1 = __uint_as_float(r1.y);
        float w2 = __uint_as_float(r2.y), w3 = __uint_as_float(r3.y);
        ushort4 p0 = *(const ushort4*)(xc + (size_t)r0.x * DD);
        ushort4 p1 = *(const ushort4*)(xc + (size_t)r1.x * DD);
        ushort4 p2 = *(const ushort4*)(xc + (size_t)r2.x * DD);
        ushort4 p3 = *(const ushort4*)(xc + (size_t)r3.x * DD);
        acc.x += w0 * bf2f(p0.x) + w1 * bf2f(p1.x) + w2 * bf2f(p2.x) + w3 * bf2f(p3.x);
        acc.y += w0 * bf2f(p0.y) + w1 * bf2f(p1.y) + w2 * bf2f(p2.y) + w3 * bf2f(p3.y);
        acc.z += w0 * bf2f(p0.z) + w1 * bf2f(p1.z) + w2 * bf2f(p2.z) + w3 * bf2f(p3.z);
        acc.w += w0 * bf2f(p0.w) + w1 * bf2f(p1.w) + w2 * bf2f(p2.w) + w3 * bf2f(p3.w);
    }
    for (; e < e1; ++e) {
        uint2 r0 = csr[e];
        float w0 = __uint_as_float(r0.y);
        ushort4 p0 = *(const ushort4*)(xc + (size_t)r0.x * DD);
        acc.x += w0 * bf2f(p0.x);
        acc.y += w0 * bf2f(p0.y);
        acc.z += w0 * bf2f(p0.z);
        acc.w += w0 * bf2f(p0.w);
    }
    ushort4 oh;
    oh.x = f2bf(acc.x); oh.y = f2bf(acc.y); oh.z = f2bf(acc.z); oh.w = f2bf(acc.w);
    *(ushort4*)(gH + nout) = oh;
}

// ---------------------------------------------------------------- GRU layer kernel (32-row tiles)
// 64 accumulator regs/thread + ~50 live → fits 4 waves/SIMD without spill.
__global__ __launch_bounds__(256, 4) void gru_kernel(const ush_t* __restrict__ xin,
                                                     const ush_t* __restrict__ gH,
                                                     ush_t* __restrict__ xout,
                                                     const ush_t* __restrict__ WB,
                                                     const float* __restrict__ bih,
                                                     const float* __restrict__ bhh,
                                                     int layer, int is_last,
                                                     const float* __restrict__ gw,
                                                     const float* __restrict__ gb,
                                                     float* __restrict__ accum,
                                                     float* __restrict__ den) {
    __shared__ ush_t sX[32 * 136];
    __shared__ float pl[32];
    __shared__ float sT[128];
    int t = threadIdx.x;
    int tb = blockIdx.x;
    int n0 = tb * 32;
    // --- stage x tile (row-major, padded pitch)
    #pragma unroll
    for (int it = 0; it < 2; ++it) {
        int idx = it * 256 + t;          // 512 chunks of 16B
        int row = idx >> 4, seg = idx & 15;
        ushort8_t v = *(const ushort8_t*)(xin + (size_t)(n0 + row) * DD + seg * 8);
        *(ushort8_t*)(sX + row * 136 + seg * 8) = v;
    }
    __syncthreads();
    // --- MFMA
    int l = t & 63, w = t >> 6;
    int lg = l >> 4, lc = l & 15;
    floatx4 accR[2][2], accZ[2][2], accN[2][2], accI[2][2];
    #pragma unroll
    for (int i = 0; i < 2; ++i)
        #pragma unroll
        for (int j = 0; j < 2; ++j) {
            accR[i][j] = (floatx4)0.f; accZ[i][j] = (floatx4)0.f;
            accN[i][j] = (floatx4)0.f; accI[i][j] = (floatx4)0.f;
        }
    int gbase = (tb >> 2) * 16384 + (tb & 3) * 1024 + lg * 128 + lc * 8;
    #pragma unroll
    for (int pass = 0; pass < 2; ++pass) {
        int matbase = pass ? (3 + layer * 3) : 0;
        #pragma unroll
        for (int kc = 0; kc < 4; ++kc) {
            short8 aHf[2];
            if (pass == 0) {
                #pragma unroll
                for (int i = 0; i < 2; ++i)
                    aHf[i] = *(const short8*)(sX + (i * 16 + lc) * 136 + kc * 32 + lg * 8);
            } else {
                #pragma unroll
                for (int i = 0; i < 2; ++i)
                    aHf[i] = *(const short8*)(gH + gbase + kc * 4096 + i * 512);
            }
            #pragma unroll
            for (int m3 = 0; m3 < 3; ++m3) {
                floatx4 (*accp)[2] = (m3 == 0) ? accR : (m3 == 1) ? accZ : (pass ? accI : accN);
                const ush_t* wb = WB + (size_t)((matbase + m3) * 4 + kc) * 4096;
                #pragma unroll
                for (int j = 0; j < 2; ++j) {
                    int boff = (((w * 2 + j) * 4 + lg) * 16 + lc) * 8;
                    short8 bH = *(const short8*)(wb + boff);
                    #pragma unroll
                    for (int i = 0; i < 2; ++i)
                        accp[i][j] = __builtin_amdgcn_mfma_f32_16x16x32_bf16(aHf[i], bH, accp[i][j], 0, 0, 0);
                }
            }
        }
    }
    __syncthreads();   // all sX A-frag reads done before overwrite
    // --- gates + blend, in-place into sX
    #pragma unroll
    for (int j = 0; j < 2; ++j) {
        int col = w * 32 + j * 16 + lc;
        float bIr = bih[col],       bHr = bhh[col];
        float bIz = bih[128 + col], bHz = bhh[128 + col];
        float bIn = bih[256 + col], bHn = bhh[256 + col];
        #pragma unroll
        for (int i = 0; i < 2; ++i)
            #pragma unroll
            for (int r = 0; r < 4; ++r) {
                int row = i * 16 + lg * 4 + r;
                float v = 0.f;
                if (n0 + row < NN) {
                    float rr = sigf(accR[i][j][r] + bIr + bHr);
                    float zz = sigf(accZ[i][j][r] + bIz + bHz);
                    float nn = tanhf_fast(accI[i][j][r] + bIn + rr * (accN[i][j][r] + bHn));
                    float h = bf2f(sX[row * 136 + col]);
                    v = (1.0f - zz) * nn + zz * h;
                }
                sX[row * 136 + col] = f2bf(v);
            }
    }
    __syncthreads();
    if (!is_last) {
        // --- coalesced row-major write-out
        #pragma unroll
        for (int it = 0; it < 2; ++it) {
            int idx = it * 256 + t;
            int row = idx >> 4, seg = idx & 15;
            ushort8_t v = *(const ushort8_t*)(sX + row * 136 + seg * 8);
            *(ushort8_t*)(xout + (size_t)(n0 + row) * DD + seg * 8) = v;
        }
    } else {
        // --- fused global-attention pooling (replicated accumulators)
        int row = t >> 3, q = t & 7;      // 8 threads per row, 16 cols each
        float s = 0.f;
        #pragma unroll
        for (int e = 0; e < 16; ++e)
            s += bf2f(sX[row * 136 + q * 16 + e]) * gw[q * 16 + e];
        s += __shfl_xor(s, 1);
        s += __shfl_xor(s, 2);
        s += __shfl_xor(s, 4);
        if (q == 0)
            pl[row] = (n0 + row < NN) ? __expf(sigf(s + gb[0])) : 0.f;
        __syncthreads();
        int cc = t & 127, half = t >> 7;
        float acc = 0.f;
        #pragma unroll
        for (int r = 0; r < 16; ++r)
            acc += pl[half * 16 + r] * bf2f(sX[(half * 16 + r) * 136 + cc]);
        if (half == 0) sT[cc] = acc;
        __syncthreads();
        if (half == 1) atomicAdd(&accum[(tb & 63) * 128 + cc], acc + sT[cc]);
        if (t < 32) {
            float v = pl[t];
            #pragma unroll
            for (int o = 16; o > 0; o >>= 1) v += __shfl_xor(v, o);
            if (t == 0) atomicAdd(&den[tb & 63], v);
        }
    }
}

__global__ void finalize_kernel(const float* __restrict__ accum, const float* __restrict__ den,
                                float* __restrict__ out) {
    __shared__ float dsum;
    int d = threadIdx.x;   // 128
    float s = 0.f;
    for (int rep = 0; rep < 64; ++rep) s += accum[rep * 128 + d];
    if (d == 0) {
        float ds = 0.f;
        for (int rep = 0; rep < 64; ++rep) ds += den[rep];
        dsum = ds;
    }
    __syncthreads();
    out[d] = s / dsum;
}

// ---------------------------------------------------------------- launch
extern "C" void kernel_launch(void* const* d_in, const int* in_sizes, int n_in,
                              void* d_out, int out_size, void* d_ws, size_t ws_size,
                              hipStream_t stream) {
    const int*   node_ids    = (const int*)d_in[0];
    const int*   edges       = (const int*)d_in[1];
    const int*   edge_types  = (const int*)d_in[2];
    const float* embed_table = (const float*)d_in[3];
    const float* edge_tab    = (const float*)d_in[4];
    const float* ggnn_w      = (const float*)d_in[5];
    const float* Wih         = (const float*)d_in[6];
    const float* Whh         = (const float*)d_in[7];
    const float* bih         = (const float*)d_in[8];
    const float* bhh         = (const float*)d_in[9];
    const float* gate_w      = (const float*)d_in[10];
    const float* gate_b      = (const float*)d_in[11];
    float* out = (float*)d_out;

    const size_t PL = (size_t)NPAD * DD;
    ush_t* wsb  = (ush_t*)d_ws;
    ush_t* xA   = wsb;
    ush_t* xB   = xA + PL;
    ush_t* gH   = xB + PL;          // frag plane
    ush_t* WB   = gH + PL;          // 15 mats * 4 chunks * 4096
    uint2* csr  = (uint2*)(WB + 15 * 4 * 4096);   // E records (8B-aligned)
    float* accum = (float*)(csr + NE);  // 64 * 128
    float* den   = accum + 64 * 128;    // 64
    float* rm    = den + 64;            // 7(+1)
    int*   rp    = (int*)(rm + 8);      // N+1
    int*   fill  = rp + NN + 1;         // N
    int*   bsum  = fill + NN;           // 128
    int*   boff  = bsum + 128;          // 128

    const int* src = edges;
    const int* dst = edges + NE;

    // one-time prep: memset, mega-prep (embed+hist+cprep+wprep+rowmean), scan chain, place
    hipMemsetAsync(fill, 0, NN * sizeof(int), stream);
    megaprep_kernel<<<MEGA_BLKS, 256, 0, stream>>>(node_ids, embed_table, xA,
                                                   dst, fill,
                                                   Wih, ggnn_w, Whh, WB,
                                                   edge_tab, rm);
    scanA_kernel<<<SCANB, 1024, 0, stream>>>(fill, rp, bsum);
    scanB_kernel<<<1, 128, 0, stream>>>(bsum, boff, accum);
    scanC_kernel<<<(NN + 255) / 256, 256, 0, stream>>>(rp, boff, fill);
    place_kernel<<<(NE + 255) / 256, 256, 0, stream>>>(src, dst, edge_types, rm, rp, fill, csr);

    // 4 layers: standalone high-occupancy gather + gru
    ush_t* x = xA;
    ush_t* xo = xB;
    for (int layer = 0; layer < 4; ++layer) {
        agg_kernel<<<(NPAD + 15) / 16, 512, 0, stream>>>(x, rp, csr, gH);
        gru_kernel<<<NT3, 256, 0, stream>>>(x, gH, xo, WB, bih, bhh,
                                            layer, layer == 3 ? 1 : 0,
                                            gate_w, gate_b, accum, den);
        ush_t* tmp = x; x = xo; xo = tmp;
    }

    finalize_kernel<<<1, 128, 0, stream>>>(accum, den, out);
}

// Round 3
// 510.951 us; speedup vs baseline: 1.2374x; 1.0207x over previous
//
#include <hip/hip_runtime.h>
#include <math.h>

#define NN 100000
#define NPAD 100096
#define NT64 1564     // NPAD / 64 (gru blocks)
#define NE 800000
#define DD 128
#define SCANB 98      // ceil(NN/1024)

#define EMB_BLKS 6256     // NPAD*16/256
#define HIST_BLKS 3125    // NE/256
#define CPREP_BLKS 96
#define WPREP_BLKS 192
#define MEGA_BLKS (EMB_BLKS + HIST_BLKS + CPREP_BLKS + WPREP_BLKS + 7)

typedef __attribute__((ext_vector_type(8))) short short8;
typedef __attribute__((ext_vector_type(4))) float floatx4;
typedef unsigned short ush_t;
typedef __attribute__((ext_vector_type(8))) unsigned short ushort8_t;

__device__ __forceinline__ ush_t f2bf(float f) {
    unsigned u = __float_as_uint(f);
    return (ush_t)((u + 0x7fffu + ((u >> 16) & 1u)) >> 16);
}
__device__ __forceinline__ float bf2f(ush_t h) {
    return __uint_as_float((unsigned)h << 16);
}
__device__ __forceinline__ float sigf(float x) {
    return __builtin_amdgcn_rcpf(1.0f + __expf(-x));
}
__device__ __forceinline__ float tanhf_fast(float x) {
    x = fminf(fmaxf(x, -20.0f), 20.0f);
    float e = __expf(2.0f * x);
    return 1.0f - 2.0f * __builtin_amdgcn_rcpf(e + 1.0f);
}

// ---------------------------------------------------------------- mega-prep: embed + hist + cprep + wprep + rowmean
__global__ __launch_bounds__(256) void megaprep_kernel(
        const int* __restrict__ ids, const float* __restrict__ tab, ush_t* __restrict__ x,
        const int* __restrict__ dst, int* __restrict__ fill,
        const float* __restrict__ Wih, const float* __restrict__ G,
        const float* __restrict__ Whh, ush_t* __restrict__ WB,
        const float* __restrict__ etab, float* __restrict__ rm) {
    __shared__ float sW[16 * 128];
    int b = blockIdx.x;
    int t = threadIdx.x;
    if (b < EMB_BLKS) {
        // ---- embedding gather -> bf16 row-major
        int tid = b * 256 + t;
        int n = tid >> 4, c = tid & 15;
        ushort8_t h;
        if (n < NN) {
            const float4* srcp = (const float4*)(tab + (size_t)(ids[n] + 1) * DD + c * 8);
            float4 v0 = srcp[0], v1 = srcp[1];
            h[0] = f2bf(v0.x); h[1] = f2bf(v0.y); h[2] = f2bf(v0.z); h[3] = f2bf(v0.w);
            h[4] = f2bf(v1.x); h[5] = f2bf(v1.y); h[6] = f2bf(v1.z); h[7] = f2bf(v1.w);
        } else {
            #pragma unroll
            for (int e = 0; e < 8; ++e) h[e] = 0;
        }
        if (n < NPAD)
            *(ushort8_t*)(x + (size_t)n * DD + c * 8) = h;
        return;
    }
    b -= EMB_BLKS;
    if (b < HIST_BLKS) {
        // ---- degree histogram
        int e = b * 256 + t;
        if (e < NE) atomicAdd(&fill[dst[e]], 1);
        return;
    }
    b -= HIST_BLKS;
    if (b < CPREP_BLKS) {
        // ---- combined weights: C[l,g] = W_l @ Wih_g^T
        int mat = b >> 3, rg = b & 7;
        int l = mat / 3, g = mat % 3;
        int k0 = rg * 16;
        #pragma unroll
        for (int it = 0; it < 8; ++it) {
            int idx = it * 256 + t;
            sW[idx] = G[(size_t)l * 16384 + (size_t)(k0 + (idx >> 7)) * 128 + (idx & 127)];
        }
        __syncthreads();
        int col = t & 127, kh = t >> 7;
        float acc[8];
        #pragma unroll
        for (int e = 0; e < 8; ++e) acc[e] = 0.f;
        const float* wr = Wih + (size_t)(g * 128 + col) * 128;
        for (int j = 0; j < 128; ++j) {
            float wv = wr[j];
            #pragma unroll
            for (int e = 0; e < 8; ++e) acc[e] += sW[(kh * 8 + e) * 128 + j] * wv;
        }
        int M = 3 + l * 3 + g;
        #pragma unroll
        for (int e = 0; e < 8; ++e) {
            int k = k0 + kh * 8 + e;
            int chunk = k >> 5, klo = k & 31;
            int inoff = ((col >> 4) * 4 + (klo >> 3)) * 128 + (col & 15) * 8 + (klo & 7);
            WB[(size_t)(M * 4 + chunk) * 4096 + inoff] = f2bf(acc[e]);
        }
        return;
    }
    b -= CPREP_BLKS;
    if (b < WPREP_BLKS) {
        // ---- Whh gates -> WB mats 0..2
        int idx = b * 256 + t;
        int mat = idx >> 14;
        int rem = idx & 16383;
        int col = rem & 127, kk = rem >> 7;
        float w = Whh[((size_t)mat * 128 + col) * 128 + kk];
        int chunk = kk >> 5, klo = kk & 31;
        int inoff = ((col >> 4) * 4 + (klo >> 3)) * 128 + (col & 15) * 8 + (klo & 7);
        WB[(size_t)(mat * 4 + chunk) * 4096 + inoff] = f2bf(w);
        return;
    }
    b -= WPREP_BLKS;
    {
        // ---- row means of edge-type table (7 blocks)
        int r = b;
        float v = (t < 128) ? etab[r * DD + t] : 0.f;
        #pragma unroll
        for (int o = 32; o > 0; o >>= 1) v += __shfl_xor(v, o);
        if ((t & 63) == 0) sW[t >> 6] = v;
        __syncthreads();
        if (t == 0) rm[r] = (sW[0] + sW[1]) * (1.0f / DD);
    }
}

// ---------------------------------------------------------------- CSR build scans
__global__ __launch_bounds__(1024) void scanA_kernel(const int* __restrict__ cnt,
                                                     int* __restrict__ rp,
                                                     int* __restrict__ bsum) {
    __shared__ int wsum[16];
    int t = threadIdx.x;
    int i = blockIdx.x * 1024 + t;
    int lane = t & 63, w = t >> 6;
    int v = (i < NN) ? cnt[i] : 0;
    int sv = v;
    #pragma unroll
    for (int off = 1; off < 64; off <<= 1) {
        int u = __shfl_up(sv, off);
        if (lane >= off) sv += u;
    }
    if (lane == 63) wsum[w] = sv;
    __syncthreads();
    int woff = 0;
    #pragma unroll
    for (int j = 0; j < 16; ++j) woff += (j < w) ? wsum[j] : 0;
    if (i < NN) rp[i + 1] = sv + woff;
    if (t == 1023) bsum[blockIdx.x] = sv + woff;
}

__global__ __launch_bounds__(128) void scanB_kernel(const int* __restrict__ bsum,
                                                    int* __restrict__ boff,
                                                    float* __restrict__ accz) {
    __shared__ int wsum[2];
    int t = threadIdx.x;
    int lane = t & 63, w = t >> 6;
    int v = (t < SCANB) ? bsum[t] : 0;
    int sv = v;
    #pragma unroll
    for (int off = 1; off < 64; off <<= 1) {
        int u = __shfl_up(sv, off);
        if (lane >= off) sv += u;
    }
    if (lane == 63) wsum[w] = sv;
    __syncthreads();
    int woff = (w == 1) ? wsum[0] : 0;
    if (t < SCANB) boff[t] = sv + woff - v;   // exclusive
    // fold: zero the pooling accumulators (replaces a memset dispatch)
    for (int i = t; i < 64 * 128 + 64; i += 128) accz[i] = 0.f;
}

__global__ __launch_bounds__(256) void scanC_kernel(int* __restrict__ rp,
                                                    const int* __restrict__ boff,
                                                    int* __restrict__ fill) {
    int i = blockIdx.x * 256 + threadIdx.x;
    if (i == 0) rp[0] = 0;
    if (i < NN) {
        rp[i + 1] += boff[i >> 10];
        fill[i] = 0;   // fold: re-zero fill for place (replaces a memset dispatch)
    }
}

// single interleaved 8B record per edge: (src, weight-bits)
__global__ void place_kernel(const int* __restrict__ src, const int* __restrict__ dst,
                             const int* __restrict__ et, const float* __restrict__ rm,
                             const int* __restrict__ rp, int* __restrict__ fill,
                             uint2* __restrict__ csr) {
    int e = blockIdx.x * 256 + threadIdx.x;
    if (e < NE) {
        int d = dst[e];
        int pos = rp[d] + atomicAdd(&fill[d], 1);
        uint2 rec;
        rec.x = (unsigned)src[e];
        rec.y = __float_as_uint(rm[et[e] - 1]);
        csr[pos] = rec;
    }
}

// ---------------------------------------------------------------- CSR gather: g = sum ew*x[src]
__global__ __launch_bounds__(512) void agg_kernel(const ush_t* __restrict__ x,
                                                  const int* __restrict__ rp,
                                                  const uint2* __restrict__ csr,
                                                  ush_t* __restrict__ gH) {
    int t = threadIdx.x;
    int grp = t >> 5, c = t & 31;
    int n = blockIdx.x * 16 + grp;
    if (n >= NPAD) return;
    int nout = ((n >> 7) << 14) + ((c >> 3) << 12) + (((n >> 4) & 7) << 9)
             + (((c >> 1) & 3) << 7) + ((n & 15) << 3) + ((c & 1) << 2);
    if (n >= NN) {
        *(ushort4*)(gH + nout) = make_ushort4(0, 0, 0, 0);
        return;
    }
    const ush_t* xc = x + c * 4;
    int e0 = rp[n], e1 = rp[n + 1];
    float4 acc = make_float4(0.f, 0.f, 0.f, 0.f);
    int e = e0;
    for (; e + 3 < e1; e += 4) {
        uint2 r0 = csr[e], r1 = csr[e + 1], r2 = csr[e + 2], r3 = csr[e + 3];
        float w0 = __uint_as_float(r0.y), w1 = __uint_as_float(r1.y);
        float w2 = __uint_as_float(r2.y), w3 = __uint_as_float(r3.y);
        ushort4 p0 = *(const ushort4*)(xc + (size_t)r0.x * DD);
        ushort4 p1 = *(const ushort4*)(xc + (size_t)r1.x * DD);
        ushort4 p2 = *(const ushort4*)(xc + (size_t)r2.x * DD);
        ushort4 p3 = *(const ushort4*)(xc + (size_t)r3.x * DD);
        acc.x += w0 * bf2f(p0.x) + w1 * bf2f(p1.x) + w2 * bf2f(p2.x) + w3 * bf2f(p3.x);
        acc.y += w0 * bf2f(p0.y) + w1 * bf2f(p1.y) + w2 * bf2f(p2.y) + w3 * bf2f(p3.y);
        acc.z += w0 * bf2f(p0.z) + w1 * bf2f(p1.z) + w2 * bf2f(p2.z) + w3 * bf2f(p3.z);
        acc.w += w0 * bf2f(p0.w) + w1 * bf2f(p1.w) + w2 * bf2f(p2.w) + w3 * bf2f(p3.w);
    }
    for (; e < e1; ++e) {
        uint2 r0 = csr[e];
        float w0 = __uint_as_float(r0.y);
        ushort4 p0 = *(const ushort4*)(xc + (size_t)r0.x * DD);
        acc.x += w0 * bf2f(p0.x);
        acc.y += w0 * bf2f(p0.y);
        acc.z += w0 * bf2f(p0.z);
        acc.w += w0 * bf2f(p0.w);
    }
    ushort4 oh;
    oh.x = f2bf(acc.x); oh.y = f2bf(acc.y); oh.z = f2bf(acc.z); oh.w = f2bf(acc.w);
    *(ushort4*)(gH + nout) = oh;
}

// ---------------------------------------------------------------- GRU layer kernel (64-row tiles, 8 waves)
// Each wave owns ONE 16-col tile (w=0..7) over 4 row-tiles (i=0..3):
// acc = 4 gates x 4 i x f32x4 = 64 AGPRs (same budget as the 32-row version),
// but each B-fragment load now feeds 4 MFMAs instead of 2 — halves WB L2
// traffic per row and per-thread load count (58 -> ~42).
__global__ __launch_bounds__(512, 4) void gru_kernel(const ush_t* __restrict__ xin,
                                                     const ush_t* __restrict__ gH,
                                                     ush_t* __restrict__ xout,
                                                     const ush_t* __restrict__ WB,
                                                     const float* __restrict__ bih,
                                                     const float* __restrict__ bhh,
                                                     int layer, int is_last,
                                                     const float* __restrict__ gw,
                                                     const float* __restrict__ gb,
                                                     float* __restrict__ accum,
                                                     float* __restrict__ den) {
    __shared__ ush_t sX[64 * 136];
    __shared__ float pl[64];
    int t = threadIdx.x;
    int tb = blockIdx.x;
    int n0 = tb * 64;
    // --- stage x tile (row-major, padded pitch)
    #pragma unroll
    for (int it = 0; it < 2; ++it) {
        int idx = it * 512 + t;          // 1024 chunks of 16B
        int row = idx >> 4, seg = idx & 15;
        ushort8_t v = *(const ushort8_t*)(xin + (size_t)(n0 + row) * DD + seg * 8);
        *(ushort8_t*)(sX + row * 136 + seg * 8) = v;
    }
    __syncthreads();
    // --- MFMA
    int l = t & 63, w = t >> 6;          // w = 0..7: column tile
    int lg = l >> 4, lc = l & 15;
    floatx4 accR[4], accZ[4], accN[4], accI[4];
    #pragma unroll
    for (int i = 0; i < 4; ++i) {
        accR[i] = (floatx4)0.f; accZ[i] = (floatx4)0.f;
        accN[i] = (floatx4)0.f; accI[i] = (floatx4)0.f;
    }
    int gbase = (tb >> 1) * 16384 + (tb & 1) * 2048 + lg * 128 + lc * 8;
    int boff = ((w * 4 + lg) * 16 + lc) * 8;
    #pragma unroll
    for (int pass = 0; pass < 2; ++pass) {
        int matbase = pass ? (3 + layer * 3) : 0;
        #pragma unroll
        for (int kc = 0; kc < 4; ++kc) {
            short8 aHf[4];
            if (pass == 0) {
                #pragma unroll
                for (int i = 0; i < 4; ++i)
                    aHf[i] = *(const short8*)(sX + (i * 16 + lc) * 136 + kc * 32 + lg * 8);
            } else {
                #pragma unroll
                for (int i = 0; i < 4; ++i)
                    aHf[i] = *(const short8*)(gH + gbase + kc * 4096 + i * 512);
            }
            #pragma unroll
            for (int m3 = 0; m3 < 3; ++m3) {
                floatx4* accp = (m3 == 0) ? accR : (m3 == 1) ? accZ : (pass ? accI : accN);
                const ush_t* wb = WB + (size_t)((matbase + m3) * 4 + kc) * 4096;
                short8 bH = *(const short8*)(wb + boff);
                #pragma unroll
                for (int i = 0; i < 4; ++i)
                    accp[i] = __builtin_amdgcn_mfma_f32_16x16x32_bf16(aHf[i], bH, accp[i], 0, 0, 0);
            }
        }
    }
    __syncthreads();   // all sX A-frag reads done before overwrite
    // --- gates + blend, in-place into sX
    {
        int col = w * 16 + lc;
        float bIr = bih[col],       bHr = bhh[col];
        float bIz = bih[128 + col], bHz = bhh[128 + col];
        float bIn = bih[256 + col], bHn = bhh[256 + col];
        #pragma unroll
        for (int i = 0; i < 4; ++i)
            #pragma unroll
            for (int r = 0; r < 4; ++r) {
                int row = i * 16 + lg * 4 + r;
                float v = 0.f;
                if (n0 + row < NN) {
                    float rr = sigf(accR[i][r] + bIr + bHr);
                    float zz = sigf(accZ[i][r] + bIz + bHz);
                    float nn = tanhf_fast(accI[i][r] + bIn + rr * (accN[i][r] + bHn));
                    float h = bf2f(sX[row * 136 + col]);
                    v = (1.0f - zz) * nn + zz * h;
                }
                sX[row * 136 + col] = f2bf(v);
            }
    }
    __syncthreads();
    if (!is_last) {
        // --- coalesced row-major write-out
        #pragma unroll
        for (int it = 0; it < 2; ++it) {
            int idx = it * 512 + t;
            int row = idx >> 4, seg = idx & 15;
            ushort8_t v = *(const ushort8_t*)(sX + row * 136 + seg * 8);
            *(ushort8_t*)(xout + (size_t)(n0 + row) * DD + seg * 8) = v;
        }
    } else {
        // --- fused global-attention pooling (replicated accumulators)
        int row = t >> 3, q = t & 7;      // 8 threads per row, 16 cols each
        float s = 0.f;
        #pragma unroll
        for (int e = 0; e < 16; ++e)
            s += bf2f(sX[row * 136 + q * 16 + e]) * gw[q * 16 + e];
        s += __shfl_xor(s, 1);
        s += __shfl_xor(s, 2);
        s += __shfl_xor(s, 4);
        if (q == 0)
            pl[row] = (n0 + row < NN) ? __expf(sigf(s + gb[0])) : 0.f;
        __syncthreads();
        int cc = t & 127, qr = t >> 7;    // 4 quarters of 16 rows each
        float acc = 0.f;
        #pragma unroll
        for (int r = 0; r < 16; ++r)
            acc += pl[qr * 16 + r] * bf2f(sX[(qr * 16 + r) * 136 + cc]);
        atomicAdd(&accum[(tb & 63) * 128 + cc], acc);
        if (t < 64) {
            float v = pl[t];
            #pragma unroll
            for (int o = 32; o > 0; o >>= 1) v += __shfl_xor(v, o);
            if (t == 0) atomicAdd(&den[tb & 63], v);
        }
    }
}

__global__ void finalize_kernel(const float* __restrict__ accum, const float* __restrict__ den,
                                float* __restrict__ out) {
    __shared__ float dsum;
    int d = threadIdx.x;   // 128
    float s = 0.f;
    for (int rep = 0; rep < 64; ++rep) s += accum[rep * 128 + d];
    if (d == 0) {
        float ds = 0.f;
        for (int rep = 0; rep < 64; ++rep) ds += den[rep];
        dsum = ds;
    }
    __syncthreads();
    out[d] = s / dsum;
}

// ---------------------------------------------------------------- launch
extern "C" void kernel_launch(void* const* d_in, const int* in_sizes, int n_in,
                              void* d_out, int out_size, void* d_ws, size_t ws_size,
                              hipStream_t stream) {
    const int*   node_ids    = (const int*)d_in[0];
    const int*   edges       = (const int*)d_in[1];
    const int*   edge_types  = (const int*)d_in[2];
    const float* embed_table = (const float*)d_in[3];
    const float* edge_tab    = (const float*)d_in[4];
    const float* ggnn_w      = (const float*)d_in[5];
    const float* Wih         = (const float*)d_in[6];
    const float* Whh         = (const float*)d_in[7];
    const float* bih         = (const float*)d_in[8];
    const float* bhh         = (const float*)d_in[9];
    const float* gate_w      = (const float*)d_in[10];
    const float* gate_b      = (const float*)d_in[11];
    float* out = (float*)d_out;

    const size_t PL = (size_t)NPAD * DD;
    ush_t* wsb  = (ush_t*)d_ws;
    ush_t* xA   = wsb;
    ush_t* xB   = xA + PL;
    ush_t* gH   = xB + PL;          // frag plane
    ush_t* WB   = gH + PL;          // 15 mats * 4 chunks * 4096
    uint2* csr  = (uint2*)(WB + 15 * 4 * 4096);   // E records (8B-aligned)
    float* accum = (float*)(csr + NE);  // 64 * 128
    float* den   = accum + 64 * 128;    // 64
    float* rm    = den + 64;            // 7(+1)
    int*   rp    = (int*)(rm + 8);      // N+1
    int*   fill  = rp + NN + 1;         // N
    int*   bsum  = fill + NN;           // 128
    int*   boff  = bsum + 128;          // 128

    const int* src = edges;
    const int* dst = edges + NE;

    // one-time prep: memset, mega-prep (embed+hist+cprep+wprep+rowmean), scan chain, place
    hipMemsetAsync(fill, 0, NN * sizeof(int), stream);
    megaprep_kernel<<<MEGA_BLKS, 256, 0, stream>>>(node_ids, embed_table, xA,
                                                   dst, fill,
                                                   Wih, ggnn_w, Whh, WB,
                                                   edge_tab, rm);
    scanA_kernel<<<SCANB, 1024, 0, stream>>>(fill, rp, bsum);
    scanB_kernel<<<1, 128, 0, stream>>>(bsum, boff, accum);
    scanC_kernel<<<(NN + 255) / 256, 256, 0, stream>>>(rp, boff, fill);
    place_kernel<<<(NE + 255) / 256, 256, 0, stream>>>(src, dst, edge_types, rm, rp, fill, csr);

    // 4 layers: standalone high-occupancy gather + gru
    ush_t* x = xA;
    ush_t* xo = xB;
    for (int layer = 0; layer < 4; ++layer) {
        agg_kernel<<<(NPAD + 15) / 16, 512, 0, stream>>>(x, rp, csr, gH);
        gru_kernel<<<NT64, 512, 0, stream>>>(x, gH, xo, WB, bih, bhh,
                                             layer, layer == 3 ? 1 : 0,
                                             gate_w, gate_b, accum, den);
        ush_t* tmp = x; x = xo; xo = tmp;
    }

    finalize_kernel<<<1, 128, 0, stream>>>(accum, den, out);
}

// Round 4
// 485.493 us; speedup vs baseline: 1.3023x; 1.0524x over previous
//
#include <hip/hip_runtime.h>
#include <math.h>

#define NN 100000
#define NPAD 100096
#define NT64 1564     // NPAD / 64 (gru blocks)
#define NE 800000
#define DD 128
#define SCANB 98      // ceil(NN/1024)

#define EMB_BLKS 6256     // NPAD*16/256
#define HIST_BLKS 3125    // NE/256
#define CPREP_BLKS 96
#define WPREP_BLKS 192
#define MEGA_BLKS (EMB_BLKS + HIST_BLKS + CPREP_BLKS + WPREP_BLKS + 7 + 1)

typedef __attribute__((ext_vector_type(8))) short short8;
typedef __attribute__((ext_vector_type(4))) float floatx4;
typedef unsigned short ush_t;
typedef __attribute__((ext_vector_type(8))) unsigned short ushort8_t;

__device__ __forceinline__ ush_t f2bf(float f) {
    unsigned u = __float_as_uint(f);
    return (ush_t)((u + 0x7fffu + ((u >> 16) & 1u)) >> 16);
}
__device__ __forceinline__ float bf2f(ush_t h) {
    return __uint_as_float((unsigned)h << 16);
}
__device__ __forceinline__ float sigf(float x) {
    return __builtin_amdgcn_rcpf(1.0f + __expf(-x));
}
__device__ __forceinline__ float tanhf_fast(float x) {
    x = fminf(fmaxf(x, -20.0f), 20.0f);
    float e = __expf(2.0f * x);
    return 1.0f - 2.0f * __builtin_amdgcn_rcpf(e + 1.0f);
}

// ---------------------------------------------------------------- mega-prep: embed + hist + cprep + wprep + rowmean + accz
__global__ __launch_bounds__(256) void megaprep_kernel(
        const int* __restrict__ ids, const float* __restrict__ tab, ush_t* __restrict__ x,
        const int* __restrict__ dst, int* __restrict__ fill,
        const float* __restrict__ Wih, const float* __restrict__ G,
        const float* __restrict__ Whh, ush_t* __restrict__ WB,
        const float* __restrict__ etab, float* __restrict__ rm,
        float* __restrict__ accz) {
    __shared__ float sW[16 * 128];
    int b = blockIdx.x;
    int t = threadIdx.x;
    if (b < EMB_BLKS) {
        // ---- embedding gather -> bf16 row-major
        int tid = b * 256 + t;
        int n = tid >> 4, c = tid & 15;
        ushort8_t h;
        if (n < NN) {
            const float4* srcp = (const float4*)(tab + (size_t)(ids[n] + 1) * DD + c * 8);
            float4 v0 = srcp[0], v1 = srcp[1];
            h[0] = f2bf(v0.x); h[1] = f2bf(v0.y); h[2] = f2bf(v0.z); h[3] = f2bf(v0.w);
            h[4] = f2bf(v1.x); h[5] = f2bf(v1.y); h[6] = f2bf(v1.z); h[7] = f2bf(v1.w);
        } else {
            #pragma unroll
            for (int e = 0; e < 8; ++e) h[e] = 0;
        }
        if (n < NPAD)
            *(ushort8_t*)(x + (size_t)n * DD + c * 8) = h;
        return;
    }
    b -= EMB_BLKS;
    if (b < HIST_BLKS) {
        // ---- degree histogram
        int e = b * 256 + t;
        if (e < NE) atomicAdd(&fill[dst[e]], 1);
        return;
    }
    b -= HIST_BLKS;
    if (b < CPREP_BLKS) {
        // ---- combined weights: C[l,g] = W_l @ Wih_g^T
        int mat = b >> 3, rg = b & 7;
        int l = mat / 3, g = mat % 3;
        int k0 = rg * 16;
        #pragma unroll
        for (int it = 0; it < 8; ++it) {
            int idx = it * 256 + t;
            sW[idx] = G[(size_t)l * 16384 + (size_t)(k0 + (idx >> 7)) * 128 + (idx & 127)];
        }
        __syncthreads();
        int col = t & 127, kh = t >> 7;
        float acc[8];
        #pragma unroll
        for (int e = 0; e < 8; ++e) acc[e] = 0.f;
        const float* wr = Wih + (size_t)(g * 128 + col) * 128;
        for (int j = 0; j < 128; ++j) {
            float wv = wr[j];
            #pragma unroll
            for (int e = 0; e < 8; ++e) acc[e] += sW[(kh * 8 + e) * 128 + j] * wv;
        }
        int M = 3 + l * 3 + g;
        #pragma unroll
        for (int e = 0; e < 8; ++e) {
            int k = k0 + kh * 8 + e;
            int chunk = k >> 5, klo = k & 31;
            int inoff = ((col >> 4) * 4 + (klo >> 3)) * 128 + (col & 15) * 8 + (klo & 7);
            WB[(size_t)(M * 4 + chunk) * 4096 + inoff] = f2bf(acc[e]);
        }
        return;
    }
    b -= CPREP_BLKS;
    if (b < WPREP_BLKS) {
        // ---- Whh gates -> WB mats 0..2
        int idx = b * 256 + t;
        int mat = idx >> 14;
        int rem = idx & 16383;
        int col = rem & 127, kk = rem >> 7;
        float w = Whh[((size_t)mat * 128 + col) * 128 + kk];
        int chunk = kk >> 5, klo = kk & 31;
        int inoff = ((col >> 4) * 4 + (klo >> 3)) * 128 + (col & 15) * 8 + (klo & 7);
        WB[(size_t)(mat * 4 + chunk) * 4096 + inoff] = f2bf(w);
        return;
    }
    b -= WPREP_BLKS;
    if (b < 7) {
        // ---- row means of edge-type table (7 blocks)
        int r = b;
        float v = (t < 128) ? etab[r * DD + t] : 0.f;
        #pragma unroll
        for (int o = 32; o > 0; o >>= 1) v += __shfl_xor(v, o);
        if ((t & 63) == 0) sW[t >> 6] = v;
        __syncthreads();
        if (t == 0) rm[r] = (sW[0] + sW[1]) * (1.0f / DD);
        return;
    }
    // ---- zero pooling accumulators (1 block)
    for (int i = t; i < 64 * 128 + 64; i += 256) accz[i] = 0.f;
}

// ---------------------------------------------------------------- CSR build scans
__global__ __launch_bounds__(1024) void scanA_kernel(const int* __restrict__ cnt,
                                                     int* __restrict__ rp,
                                                     int* __restrict__ bsum) {
    __shared__ int wsum[16];
    int t = threadIdx.x;
    int i = blockIdx.x * 1024 + t;
    int lane = t & 63, w = t >> 6;
    int v = (i < NN) ? cnt[i] : 0;
    int sv = v;
    #pragma unroll
    for (int off = 1; off < 64; off <<= 1) {
        int u = __shfl_up(sv, off);
        if (lane >= off) sv += u;
    }
    if (lane == 63) wsum[w] = sv;
    __syncthreads();
    int woff = 0;
    #pragma unroll
    for (int j = 0; j < 16; ++j) woff += (j < w) ? wsum[j] : 0;
    if (i < NN) rp[i + 1] = sv + woff;
    if (t == 1023) bsum[blockIdx.x] = sv + woff;
}

// scanB folded in: each block recomputes the exclusive prefix of bsum for its
// 1024-segment with a wave-parallel masked reduce (98 L2-hot loads, trivial).
__global__ __launch_bounds__(256) void scanC_kernel(int* __restrict__ rp,
                                                    const int* __restrict__ bsum,
                                                    int* __restrict__ fill) {
    __shared__ int sboff;
    int t = threadIdx.x;
    int seg = blockIdx.x >> 2;       // = i>>10 for all i in this block
    if (t < 64) {
        int v = (t < seg) ? bsum[t] : 0;
        if (t + 64 < seg) v += bsum[t + 64];
        #pragma unroll
        for (int o = 32; o > 0; o >>= 1) v += __shfl_xor(v, o);
        if (t == 0) sboff = v;
    }
    __syncthreads();
    int i = blockIdx.x * 256 + t;
    if (i == 0) rp[0] = 0;
    if (i < NN) {
        rp[i + 1] += sboff;
        fill[i] = 0;   // re-zero fill for place
    }
}

// single interleaved 8B record per edge: (src, weight-bits)
__global__ void place_kernel(const int* __restrict__ src, const int* __restrict__ dst,
                             const int* __restrict__ et, const float* __restrict__ rm,
                             const int* __restrict__ rp, int* __restrict__ fill,
                             uint2* __restrict__ csr) {
    int e = blockIdx.x * 256 + threadIdx.x;
    if (e < NE) {
        int d = dst[e];
        int pos = rp[d] + atomicAdd(&fill[d], 1);
        uint2 rec;
        rec.x = (unsigned)src[e];
        rec.y = __float_as_uint(rm[et[e] - 1]);
        csr[pos] = rec;
    }
}

// ---------------------------------------------------------------- CSR gather: g = sum ew*x[src]
// 16 lanes per node, 16-B row loads: half the gather instructions, double
// bytes-in-flight per lane vs the 32-lane/8-B version (MLP-bound fix).
__global__ __launch_bounds__(512) void agg_kernel(const ush_t* __restrict__ x,
                                                  const int* __restrict__ rp,
                                                  const uint2* __restrict__ csr,
                                                  ush_t* __restrict__ gH) {
    int t = threadIdx.x;
    int grp = t >> 4, c = t & 15;
    int n = blockIdx.x * 32 + grp;
    if (n >= NPAD) return;
    int nout = ((n >> 7) << 14) + ((c >> 2) << 12) + (((n >> 4) & 7) << 9)
             + ((c & 3) << 7) + ((n & 15) << 3);
    if (n >= NN) {
        ushort8_t z;
        #pragma unroll
        for (int k = 0; k < 8; ++k) z[k] = 0;
        *(ushort8_t*)(gH + nout) = z;
        return;
    }
    const ush_t* xc = x + c * 8;
    int e0 = rp[n], e1 = rp[n + 1];
    float acc[8];
    #pragma unroll
    for (int k = 0; k < 8; ++k) acc[k] = 0.f;
    int e = e0;
    for (; e + 3 < e1; e += 4) {
        uint2 r0 = csr[e], r1 = csr[e + 1], r2 = csr[e + 2], r3 = csr[e + 3];
        float w0 = __uint_as_float(r0.y), w1 = __uint_as_float(r1.y);
        float w2 = __uint_as_float(r2.y), w3 = __uint_as_float(r3.y);
        ushort8_t p0 = *(const ushort8_t*)(xc + (size_t)r0.x * DD);
        ushort8_t p1 = *(const ushort8_t*)(xc + (size_t)r1.x * DD);
        ushort8_t p2 = *(const ushort8_t*)(xc + (size_t)r2.x * DD);
        ushort8_t p3 = *(const ushort8_t*)(xc + (size_t)r3.x * DD);
        #pragma unroll
        for (int k = 0; k < 8; ++k)
            acc[k] += w0 * bf2f(p0[k]) + w1 * bf2f(p1[k])
                    + w2 * bf2f(p2[k]) + w3 * bf2f(p3[k]);
    }
    for (; e < e1; ++e) {
        uint2 r0 = csr[e];
        float w0 = __uint_as_float(r0.y);
        ushort8_t p0 = *(const ushort8_t*)(xc + (size_t)r0.x * DD);
        #pragma unroll
        for (int k = 0; k < 8; ++k) acc[k] += w0 * bf2f(p0[k]);
    }
    ushort8_t oh;
    #pragma unroll
    for (int k = 0; k < 8; ++k) oh[k] = f2bf(acc[k]);
    *(ushort8_t*)(gH + nout) = oh;
}

// ---------------------------------------------------------------- GRU layer kernel (64-row tiles, 8 waves)
// gH tile is now STAGED IN LDS (2 coalesced loads/thread) instead of each of
// the 8 waves re-reading the full 16 KB tile from L2 as fragments (was 128 KB
// of L2 reads per block). Per-thread global loads: 42 -> ~28.
__global__ __launch_bounds__(512, 4) void gru_kernel(const ush_t* __restrict__ xin,
                                                     const ush_t* __restrict__ gH,
                                                     ush_t* __restrict__ xout,
                                                     const ush_t* __restrict__ WB,
                                                     const float* __restrict__ bih,
                                                     const float* __restrict__ bhh,
                                                     int layer, int is_last,
                                                     const float* __restrict__ gw,
                                                     const float* __restrict__ gb,
                                                     float* __restrict__ accum,
                                                     float* __restrict__ den) {
    __shared__ ush_t sX[64 * 136];
    __shared__ ush_t sG[64 * 128];     // frag-plane chunk, linear
    __shared__ float pl[64];
    int t = threadIdx.x;
    int tb = blockIdx.x;
    int n0 = tb * 64;
    // --- stage x tile (row-major, padded pitch)
    #pragma unroll
    for (int it = 0; it < 2; ++it) {
        int idx = it * 512 + t;          // 1024 chunks of 16B
        int row = idx >> 4, seg = idx & 15;
        ushort8_t v = *(const ushort8_t*)(xin + (size_t)(n0 + row) * DD + seg * 8);
        *(ushort8_t*)(sX + row * 136 + seg * 8) = v;
    }
    // --- stage gH tile: block's data = 4 pieces of 2048 ush at 4096 stride
    {
        size_t gsrc = (size_t)(tb >> 1) * 16384 + (size_t)(tb & 1) * 2048;
        #pragma unroll
        for (int it = 0; it < 2; ++it) {
            int o = (it * 512 + t) * 8;                 // ush offset, 0..8191
            ushort8_t v = *(const ushort8_t*)(gH + gsrc + (o >> 11) * 4096 + (o & 2047));
            *(ushort8_t*)(sG + o) = v;
        }
    }
    __syncthreads();
    // --- MFMA
    int l = t & 63, w = t >> 6;          // w = 0..7: column tile
    int lg = l >> 4, lc = l & 15;
    floatx4 accR[4], accZ[4], accN[4], accI[4];
    #pragma unroll
    for (int i = 0; i < 4; ++i) {
        accR[i] = (floatx4)0.f; accZ[i] = (floatx4)0.f;
        accN[i] = (floatx4)0.f; accI[i] = (floatx4)0.f;
    }
    int boff = ((w * 4 + lg) * 16 + lc) * 8;
    #pragma unroll
    for (int pass = 0; pass < 2; ++pass) {
        int matbase = pass ? (3 + layer * 3) : 0;
        #pragma unroll
        for (int kc = 0; kc < 4; ++kc) {
            short8 aHf[4];
            if (pass == 0) {
                #pragma unroll
                for (int i = 0; i < 4; ++i)
                    aHf[i] = *(const short8*)(sX + (i * 16 + lc) * 136 + kc * 32 + lg * 8);
            } else {
                #pragma unroll
                for (int i = 0; i < 4; ++i)
                    aHf[i] = *(const short8*)(sG + kc * 2048 + i * 512 + lg * 128 + lc * 8);
            }
            #pragma unroll
            for (int m3 = 0; m3 < 3; ++m3) {
                floatx4* accp = (m3 == 0) ? accR : (m3 == 1) ? accZ : (pass ? accI : accN);
                const ush_t* wb = WB + (size_t)((matbase + m3) * 4 + kc) * 4096;
                short8 bH = *(const short8*)(wb + boff);
                #pragma unroll
                for (int i = 0; i < 4; ++i)
                    accp[i] = __builtin_amdgcn_mfma_f32_16x16x32_bf16(aHf[i], bH, accp[i], 0, 0, 0);
            }
        }
    }
    __syncthreads();   // all sX A-frag reads done before overwrite
    // --- gates + blend, in-place into sX
    {
        int col = w * 16 + lc;
        float bIr = bih[col],       bHr = bhh[col];
        float bIz = bih[128 + col], bHz = bhh[128 + col];
        float bIn = bih[256 + col], bHn = bhh[256 + col];
        #pragma unroll
        for (int i = 0; i < 4; ++i)
            #pragma unroll
            for (int r = 0; r < 4; ++r) {
                int row = i * 16 + lg * 4 + r;
                float v = 0.f;
                if (n0 + row < NN) {
                    float rr = sigf(accR[i][r] + bIr + bHr);
                    float zz = sigf(accZ[i][r] + bIz + bHz);
                    float nn = tanhf_fast(accI[i][r] + bIn + rr * (accN[i][r] + bHn));
                    float h = bf2f(sX[row * 136 + col]);
                    v = (1.0f - zz) * nn + zz * h;
                }
                sX[row * 136 + col] = f2bf(v);
            }
    }
    __syncthreads();
    if (!is_last) {
        // --- coalesced row-major write-out
        #pragma unroll
        for (int it = 0; it < 2; ++it) {
            int idx = it * 512 + t;
            int row = idx >> 4, seg = idx & 15;
            ushort8_t v = *(const ushort8_t*)(sX + row * 136 + seg * 8);
            *(ushort8_t*)(xout + (size_t)(n0 + row) * DD + seg * 8) = v;
        }
    } else {
        // --- fused global-attention pooling (replicated accumulators)
        int row = t >> 3, q = t & 7;      // 8 threads per row, 16 cols each
        float s = 0.f;
        #pragma unroll
        for (int e = 0; e < 16; ++e)
            s += bf2f(sX[row * 136 + q * 16 + e]) * gw[q * 16 + e];
        s += __shfl_xor(s, 1);
        s += __shfl_xor(s, 2);
        s += __shfl_xor(s, 4);
        if (q == 0)
            pl[row] = (n0 + row < NN) ? __expf(sigf(s + gb[0])) : 0.f;
        __syncthreads();
        int cc = t & 127, qr = t >> 7;    // 4 quarters of 16 rows each
        float acc = 0.f;
        #pragma unroll
        for (int r = 0; r < 16; ++r)
            acc += pl[qr * 16 + r] * bf2f(sX[(qr * 16 + r) * 136 + cc]);
        atomicAdd(&accum[(tb & 63) * 128 + cc], acc);
        if (t < 64) {
            float v = pl[t];
            #pragma unroll
            for (int o = 32; o > 0; o >>= 1) v += __shfl_xor(v, o);
            if (t == 0) atomicAdd(&den[tb & 63], v);
        }
    }
}

__global__ void finalize_kernel(const float* __restrict__ accum, const float* __restrict__ den,
                                float* __restrict__ out) {
    __shared__ float dsum;
    int d = threadIdx.x;   // 128
    float s = 0.f;
    for (int rep = 0; rep < 64; ++rep) s += accum[rep * 128 + d];
    if (d == 0) {
        float ds = 0.f;
        for (int rep = 0; rep < 64; ++rep) ds += den[rep];
        dsum = ds;
    }
    __syncthreads();
    out[d] = s / dsum;
}

// ---------------------------------------------------------------- launch
extern "C" void kernel_launch(void* const* d_in, const int* in_sizes, int n_in,
                              void* d_out, int out_size, void* d_ws, size_t ws_size,
                              hipStream_t stream) {
    const int*   node_ids    = (const int*)d_in[0];
    const int*   edges       = (const int*)d_in[1];
    const int*   edge_types  = (const int*)d_in[2];
    const float* embed_table = (const float*)d_in[3];
    const float* edge_tab    = (const float*)d_in[4];
    const float* ggnn_w      = (const float*)d_in[5];
    const float* Wih         = (const float*)d_in[6];
    const float* Whh         = (const float*)d_in[7];
    const float* bih         = (const float*)d_in[8];
    const float* bhh         = (const float*)d_in[9];
    const float* gate_w      = (const float*)d_in[10];
    const float* gate_b      = (const float*)d_in[11];
    float* out = (float*)d_out;

    const size_t PL = (size_t)NPAD * DD;
    ush_t* wsb  = (ush_t*)d_ws;
    ush_t* xA   = wsb;
    ush_t* xB   = xA + PL;
    ush_t* gH   = xB + PL;          // frag plane
    ush_t* WB   = gH + PL;          // 15 mats * 4 chunks * 4096
    uint2* csr  = (uint2*)(WB + 15 * 4 * 4096);   // E records (8B-aligned)
    float* accum = (float*)(csr + NE);  // 64 * 128
    float* den   = accum + 64 * 128;    // 64
    float* rm    = den + 64;            // 7(+1)
    int*   rp    = (int*)(rm + 8);      // N+1
    int*   fill  = rp + NN + 1;         // N
    int*   bsum  = fill + NN;           // 128
    int*   boff  = bsum + 128;          // 128 (unused)

    const int* src = edges;
    const int* dst = edges + NE;

    // one-time prep: memset, mega-prep, scanA, scanC (w/ folded scanB), place
    hipMemsetAsync(fill, 0, NN * sizeof(int), stream);
    megaprep_kernel<<<MEGA_BLKS, 256, 0, stream>>>(node_ids, embed_table, xA,
                                                   dst, fill,
                                                   Wih, ggnn_w, Whh, WB,
                                                   edge_tab, rm, accum);
    scanA_kernel<<<SCANB, 1024, 0, stream>>>(fill, rp, bsum);
    scanC_kernel<<<(NN + 255) / 256, 256, 0, stream>>>(rp, bsum, fill);
    place_kernel<<<(NE + 255) / 256, 256, 0, stream>>>(src, dst, edge_types, rm, rp, fill, csr);

    // 4 layers: standalone high-occupancy gather + gru
    ush_t* x = xA;
    ush_t* xo = xB;
    for (int layer = 0; layer < 4; ++layer) {
        agg_kernel<<<(NPAD + 31) / 32, 512, 0, stream>>>(x, rp, csr, gH);
        gru_kernel<<<NT64, 512, 0, stream>>>(x, gH, xo, WB, bih, bhh,
                                             layer, layer == 3 ? 1 : 0,
                                             gate_w, gate_b, accum, den);
        ush_t* tmp = x; x = xo; xo = tmp;
    }

    finalize_kernel<<<1, 128, 0, stream>>>(accum, den, out);
}